// Round 1
// baseline (11509.768 us; speedup 1.0000x reference)
//
#include <hip/hip_runtime.h>
#include <hip/hip_cooperative_groups.h>
#include <hip/hip_bf16.h>
#include <cstddef>

namespace cg = cooperative_groups;

#define BB 32
#define PP 196
#define ENCD 2048
#define EMBD 512
#define DECD 512
#define ATTD 512
#define VV 10000
#define LLEN 52
#define TT 51

// output offsets (floats)
#define OFF_PRED  0
#define OFF_TOKS  16320000
#define OFF_DLEN  16321664
#define OFF_ALPHA 16321696
#define OFF_SIDX  16641568

typedef __attribute__((ext_vector_type(8))) short short8;
typedef __attribute__((ext_vector_type(4))) float floatx4;

__device__ __forceinline__ float sigmf(float x) { return 1.0f / (1.0f + __expf(-x)); }
__device__ __forceinline__ unsigned short f2bf(float x) {
    __hip_bfloat16 h = __float2bfloat16(x);
    return *(unsigned short*)&h;
}

// ---------------------------------------------------------------- sort
__global__ void k_sort(const int* __restrict__ toks, const int* __restrict__ lens,
                       int* __restrict__ sidx, int* __restrict__ dlen, float* __restrict__ out) {
    __shared__ int s_idx[BB];
    if (threadIdx.x == 0) {
        int idx[BB], ln[BB];
        for (int i = 0; i < BB; i++) { idx[i] = i; ln[i] = lens[i]; }
        for (int i = 1; i < BB; i++) {           // stable insertion sort, descending
            int ci = idx[i], cl = ln[i]; int j = i - 1;
            while (j >= 0 && ln[j] < cl) { ln[j + 1] = ln[j]; idx[j + 1] = idx[j]; j--; }
            ln[j + 1] = cl; idx[j + 1] = ci;
        }
        for (int i = 0; i < BB; i++) {
            s_idx[i] = idx[i];
            sidx[i] = idx[i];
            int d = ln[i] - 1;
            dlen[i] = d;
            out[OFF_DLEN + i] = (float)d;
            out[OFF_SIDX + i] = (float)idx[i];
        }
    }
    __syncthreads();
    for (int i = threadIdx.x; i < BB * LLEN; i += blockDim.x) {
        int b = i / LLEN, l = i % LLEN;
        out[OFF_TOKS + i] = (float)toks[s_idx[b] * LLEN + l];
    }
}

// ---------------------------------------------------------------- mean + h0/c0 (h -> xT tail, transposed)
__global__ void k_init(const float* __restrict__ img, const int* __restrict__ sidx,
                       const float* __restrict__ Wh0, const float* __restrict__ bh0,
                       const float* __restrict__ Wc0, const float* __restrict__ bc0,
                       float* __restrict__ xT, float* __restrict__ c) {
    int b = blockIdx.x;
    int sb = sidx[b];
    __shared__ float smean[ENCD];
    const float* ib = img + (size_t)sb * PP * ENCD;
    for (int e = threadIdx.x; e < ENCD; e += 256) {
        float acc = 0.f;
        for (int p = 0; p < PP; p++) acc += ib[(size_t)p * ENCD + e];
        smean[e] = acc * (1.0f / 196.0f);
    }
    __syncthreads();
    for (int d = threadIdx.x; d < DECD; d += 256) {
        const float* wh = Wh0 + (size_t)d * ENCD;
        const float* wc = Wc0 + (size_t)d * ENCD;
        float ah = bh0[d], ac = bc0[d];
        for (int e = 0; e < ENCD; e++) { float m = smean[e]; ah += m * wh[e]; ac += m * wc[e]; }
        xT[(2048 + d) * BB + b] = ah;     // hT
        c[b * DECD + d] = ac;
    }
}

// WfcB: bf16 convert of Wfc [10000][512], layout unchanged
__global__ void k_cvtfc(const float* __restrict__ Wfc, unsigned int* __restrict__ WfcB) {
    int base = (blockIdx.x * 256 + threadIdx.x) * 4;
    for (int j = 0; j < 4; j++) {
        int ui = base + j;                 // 0 .. 2,560,000
        const float* src = Wfc + (size_t)ui * 2;
        unsigned int lo = f2bf(src[0]), hi = f2bf(src[1]);
        WfcB[ui] = lo | (hi << 16);
    }
}

// ---------------------------------------------------------------- enc_att = img @ W_enc^T + b_enc
// M=6272, N=512, K=2048. grid (98, 2), block 256. 8x8 register tile, 64x256 block tile.
__global__ void k_enc(const float* __restrict__ img, const int* __restrict__ sidx,
                      const float* __restrict__ Wenc, const float* __restrict__ benc,
                      float* __restrict__ enc_att) {
    __shared__ float sA[16][68];
    __shared__ float sW[16][260];
    __shared__ size_t sRB[64];
    int mb = blockIdx.x, c0 = blockIdx.y * 256;
    int tid = threadIdx.x;
    int tm = tid >> 5, tn = tid & 31;
    if (tid < 64) {
        int row = mb * 64 + tid;
        int b = row / PP, p = row % PP;
        sRB[tid] = ((size_t)sidx[b] * PP + p) * ENCD;
    }
    __syncthreads();
    float acc[8][8];
#pragma unroll
    for (int i = 0; i < 8; i++)
#pragma unroll
        for (int j = 0; j < 8; j++) acc[i][j] = 0.f;

    for (int kk = 0; kk < ENCD; kk += 16) {
        {
            int m = tid >> 2, kq = tid & 3;
            float4 v = *(const float4*)(img + sRB[m] + kk + kq * 4);
            sA[kq * 4 + 0][m] = v.x; sA[kq * 4 + 1][m] = v.y;
            sA[kq * 4 + 2][m] = v.z; sA[kq * 4 + 3][m] = v.w;
        }
        {
            int col = c0 + tid;
            const float* wr = Wenc + (size_t)col * ENCD + kk;
#pragma unroll
            for (int j = 0; j < 4; j++) {
                float4 v = *(const float4*)(wr + j * 4);
                sW[j * 4 + 0][tid] = v.x; sW[j * 4 + 1][tid] = v.y;
                sW[j * 4 + 2][tid] = v.z; sW[j * 4 + 3][tid] = v.w;
            }
        }
        __syncthreads();
#pragma unroll
        for (int k = 0; k < 16; k++) {
            float4 a0 = *(const float4*)&sA[k][tm * 8];
            float4 a1 = *(const float4*)&sA[k][tm * 8 + 4];
            float4 w0 = *(const float4*)&sW[k][tn * 4];
            float4 w1 = *(const float4*)&sW[k][128 + tn * 4];
            float av[8] = {a0.x, a0.y, a0.z, a0.w, a1.x, a1.y, a1.z, a1.w};
            float wv[8] = {w0.x, w0.y, w0.z, w0.w, w1.x, w1.y, w1.z, w1.w};
#pragma unroll
            for (int i = 0; i < 8; i++)
#pragma unroll
                for (int j = 0; j < 8; j++) acc[i][j] += av[i] * wv[j];
        }
        __syncthreads();
    }
#pragma unroll
    for (int i = 0; i < 8; i++) {
        int row = mb * 64 + tm * 8 + i;
        float* orow = enc_att + (size_t)row * ATTD + c0;
        int ca = tn * 4, cb = 128 + tn * 4;
        float4 oa = {acc[i][0] + benc[c0 + ca + 0], acc[i][1] + benc[c0 + ca + 1],
                     acc[i][2] + benc[c0 + ca + 2], acc[i][3] + benc[c0 + ca + 3]};
        float4 ob = {acc[i][4] + benc[c0 + cb + 0], acc[i][5] + benc[c0 + cb + 1],
                     acc[i][6] + benc[c0 + cb + 2], acc[i][7] + benc[c0 + cb + 3]};
        *(float4*)(orow + ca) = oa;
        *(float4*)(orow + cb) = ob;
    }
}

// ---------------------------------------------------------------- g_base = emb_t @ W_ih[:, :512]^T + b_ih + b_hh
__global__ void k_gemb(const float* __restrict__ emb, const int* __restrict__ toks,
                       const int* __restrict__ sidx, const float* __restrict__ Wih,
                       const float* __restrict__ bih, const float* __restrict__ bhh,
                       float* __restrict__ gbase) {
    __shared__ float As[32][33];
    __shared__ float Ws[32][65];
    __shared__ size_t rb[32];
    int row0 = blockIdx.x * 32, col0 = blockIdx.y * 64;
    int tid = threadIdx.x;
    int tr = tid & 31, tc = tid >> 5;
    if (tid < 32) {
        int t = blockIdx.x, b = tid;
        int tok = toks[sidx[b] * LLEN + t];
        rb[tid] = (size_t)tok * EMBD;
    }
    __syncthreads();
    float acc[8] = {0, 0, 0, 0, 0, 0, 0, 0};
    for (int kk = 0; kk < EMBD; kk += 32) {
        for (int i = tid; i < 1024; i += 256) {
            int r = i >> 5, k = i & 31;
            As[r][k] = emb[rb[r] + kk + k];
        }
        for (int i = tid; i < 2048; i += 256) {
            int cc = i >> 5, k = i & 31;
            Ws[k][cc] = Wih[(size_t)(col0 + cc) * (EMBD + ENCD) + kk + k];
        }
        __syncthreads();
        for (int k = 0; k < 32; k++) {
            float a = As[tr][k];
#pragma unroll
            for (int j = 0; j < 8; j++) acc[j] += a * Ws[k][tc * 8 + j];
        }
        __syncthreads();
    }
    int row = row0 + tr;
    float* crow = gbase + (size_t)row * 2048 + col0 + tc * 8;
#pragma unroll
    for (int j = 0; j < 8; j++) {
        int col = col0 + tc * 8 + j;
        crow[j] = acc[j] + bih[col] + bhh[col];
    }
}

// ---------------------------------------------------------------- persistent cooperative loop kernel
// grid 288 x 256. 4 phases per timestep, grid.sync() between phases.
struct LoopArgs {
    float* xT; float* hp; float* gpartA; float* sraw; float* c;
    unsigned short* hB;
    const float* enc_att; const float* img; const int* sidx; const int* dlen;
    const float* gbase;
    const float* Wdec; const float* Wbeta; const float* Whh; const float* Wih;
    const float* bdec; const float* wfull; const float* bbeta;
    float* out_alpha;
};

__global__ __launch_bounds__(256, 2) void k_loop(LoopArgs A) {
    cg::grid_group grid = cg::this_grid();
    __shared__ float sh[2304];
    __shared__ int s_sb;
    const int blk = blockIdx.x, tid = threadIdx.x;

    for (int t = 0; t < TT; t++) {
        // ===== Phase A: hp[2560][32] (dec_att-pre | beta-pre) and gpartA[2048][32] = W @ h
        // 288 blocks x 16 cols. cols 0..511 -> Wdec, 512..2559 -> Wbeta, 2560..4607 -> Whh.
        {
            const int kc = tid >> 6;          // 0..3  k-chunk of 128
            const int cl = (tid >> 2) & 15;   // 0..15 col within block
            const int bg = tid & 3;           // 0..3  8-batch group
            const int col = blk * 16 + cl;
            const float* wb;
            if (col < 512)       wb = A.Wdec  + (size_t)col * 512;
            else if (col < 2560) wb = A.Wbeta + (size_t)(col - 512) * 512;
            else                 wb = A.Whh   + (size_t)(col - 2560) * 512;
            const float* wr = wb + kc * 128;
            const float* xp = A.xT + (size_t)(2048 + kc * 128) * BB + bg * 8;
            float a0=0.f,a1=0.f,a2=0.f,a3=0.f,a4=0.f,a5=0.f,a6=0.f,a7=0.f;
#pragma unroll 4
            for (int k = 0; k < 128; k++) {
                float w = wr[k];
                const float* x = xp + k * BB;
                float4 xa = *(const float4*)x;
                float4 xb = *(const float4*)(x + 4);
                a0 += w * xa.x; a1 += w * xa.y; a2 += w * xa.z; a3 += w * xa.w;
                a4 += w * xb.x; a5 += w * xb.y; a6 += w * xb.z; a7 += w * xb.w;
            }
            float* s = sh + kc * 512 + cl * 32 + bg * 8;
            s[0]=a0; s[1]=a1; s[2]=a2; s[3]=a3; s[4]=a4; s[5]=a5; s[6]=a6; s[7]=a7;
            __syncthreads();
#pragma unroll
            for (int r = 0; r < 2; r++) {
                int o = r * 256 + tid;
                int ocl = o >> 5, ob = o & 31;
                float v = sh[ocl*32+ob] + sh[512+ocl*32+ob] + sh[1024+ocl*32+ob] + sh[1536+ocl*32+ob];
                int ocol = blk * 16 + ocl;
                if (ocol < 2560) A.hp[(size_t)ocol * BB + ob] = v;
                else             A.gpartA[(size_t)(ocol - 2560) * BB + ob] = v;
            }
        }
        grid.sync();

        // ===== Phase B1: raw attention scores. 128 blocks: (b, p-quarter)
        if (blk < 128) {
            const int b = blk >> 2, pq = blk & 3;
            for (int a = tid; a < 512; a += 256) {
                sh[a]       = A.hp[(size_t)a * BB + b] + A.bdec[a];
                sh[512 + a] = A.wfull[a];
            }
            __syncthreads();
            const int wv = tid >> 6, ln = tid & 63;
            const float* eb = A.enc_att + (size_t)b * PP * ATTD;
            const int p1 = pq * 49 + 49;
            for (int p = pq * 49 + wv; p < p1; p += 4) {
                const float* er = eb + (size_t)p * ATTD;
                float acc = 0.f;
#pragma unroll
                for (int i = 0; i < 8; i++) {
                    int a = ln + i * 64;
                    acc += fmaxf(er[a] + sh[a], 0.f) * sh[512 + a];
                }
#pragma unroll
                for (int off = 32; off; off >>= 1) acc += __shfl_down(acc, off);
                if (ln == 0) A.sraw[b * 200 + p] = acc;
            }
        }
        grid.sync();

        // ===== Phase B2: softmax (redundant per block) + awe + beta-gate -> xT[0:2048)
        // 256 blocks: (b, e-chunk of 256)
        if (blk < 256) {
            const int b = blk >> 3, ec = blk & 7;
            if (tid == 0) s_sb = A.sidx[b];
            float v = (tid < PP) ? A.sraw[b * 200 + tid] : -1e30f;
            sh[256 + tid] = v;
            __syncthreads();
            for (int s = 128; s; s >>= 1) { if (tid < s) sh[256+tid] = fmaxf(sh[256+tid], sh[256+tid+s]); __syncthreads(); }
            float mx = sh[256];
            __syncthreads();
            float e = (tid < PP) ? __expf(v - mx) : 0.f;
            sh[256 + tid] = e;
            __syncthreads();
            for (int s = 128; s; s >>= 1) { if (tid < s) sh[256+tid] += sh[256+tid+s]; __syncthreads(); }
            float inv = 1.f / sh[256];
            sh[tid] = e * inv;               // sal region [0..255] (distinct from scratch)
            __syncthreads();
            const int sb = s_sb;
            const int eo = ec * 256 + tid;
            const float* ib = A.img + (size_t)sb * PP * ENCD + eo;
            float acc = 0.f;
#pragma unroll 4
            for (int p = 0; p < PP; p++) acc += sh[p] * ib[(size_t)p * ENCD];
            float graw = A.hp[(size_t)(512 + eo) * BB + b] + A.bbeta[eo];
            A.xT[(size_t)eo * BB + b] = acc * sigmf(graw);
            if (ec == 0 && tid < PP) {
                bool act = t < A.dlen[b];
                A.out_alpha[((size_t)b * TT + t) * PP + tid] = act ? sh[tid] : 0.f;
            }
        }
        grid.sync();

        // ===== Phase C: gate GEMM (awe part, k=2048) + LSTM update
        // 256 blocks; block owns dd in {2*blk, 2*blk+1} across all 4 gates.
        if (blk < 256) {
            const int kc = tid >> 5;          // 0..7  k-chunk of 256
            const int cl = (tid >> 2) & 7;    // 0..7  col = q*2+dl
            const int bg = tid & 3;           // 0..3
            const int q = cl >> 1, dl = cl & 1;
            const int dcol = blk * 2 + dl + q * 512;
            const float* wr = A.Wih + (size_t)dcol * (EMBD + ENCD) + 512 + kc * 256;
            const float* xp = A.xT + (size_t)(kc * 256) * BB + bg * 8;
            float a0=0.f,a1=0.f,a2=0.f,a3=0.f,a4=0.f,a5=0.f,a6=0.f,a7=0.f;
#pragma unroll 4
            for (int k = 0; k < 256; k++) {
                float w = wr[k];
                const float* x = xp + k * BB;
                float4 xa = *(const float4*)x;
                float4 xb = *(const float4*)(x + 4);
                a0 += w * xa.x; a1 += w * xa.y; a2 += w * xa.z; a3 += w * xa.w;
                a4 += w * xb.x; a5 += w * xb.y; a6 += w * xb.z; a7 += w * xb.w;
            }
            float* s = sh + kc * 256 + cl * 32 + bg * 8;
            s[0]=a0; s[1]=a1; s[2]=a2; s[3]=a3; s[4]=a4; s[5]=a5; s[6]=a6; s[7]=a7;
            __syncthreads();
            {
                int ocl = tid >> 5, ob = tid & 31;
                float g = 0.f;
#pragma unroll
                for (int kk = 0; kk < 8; kk++) g += sh[kk * 256 + ocl * 32 + ob];
                int oq = ocl >> 1, odl = ocl & 1;
                int odcol = blk * 2 + odl + oq * 512;
                g += A.gpartA[(size_t)odcol * BB + ob];
                g += A.gbase[((size_t)t * BB + ob) * 2048 + odcol];
                sh[2048 + ocl * 32 + ob] = g;
            }
            __syncthreads();
            if (tid < 64) {
                int b = tid & 31, dl2 = tid >> 5;
                int dd = blk * 2 + dl2;
                float gi = sh[2048 + (0 + dl2) * 32 + b];
                float gf = sh[2048 + (2 + dl2) * 32 + b];
                float gg = sh[2048 + (4 + dl2) * 32 + b];
                float go = sh[2048 + (6 + dl2) * 32 + b];
                float i_ = sigmf(gi), f_ = sigmf(gf), g_ = tanhf(gg), o_ = sigmf(go);
                float cv = A.c[b * DECD + dd];
                float cn = f_ * cv + i_ * g_;
                float hn = o_ * tanhf(cn);
                bool act = t < A.dlen[b];
                float hv;
                if (act) { A.c[b * DECD + dd] = cn; A.xT[(size_t)(2048 + dd) * BB + b] = hn; hv = hn; }
                else hv = A.xT[(size_t)(2048 + dd) * BB + b];
                A.hB[((size_t)t * BB + b) * DECD + dd] = f2bf(hv);
            }
        }
        grid.sync();
    }
}

// ---------------------------------------------------------------- predictions via bf16 MFMA
__global__ void k_pred(const unsigned short* __restrict__ hB, const unsigned short* __restrict__ WfcB,
                       const float* __restrict__ bfc, const int* __restrict__ dlen,
                       float* __restrict__ out) {
    __shared__ unsigned short sA[32 * 40];
    __shared__ unsigned short sB[256 * 40];
    int t = blockIdx.x, n0 = blockIdx.y * 256;
    int tid = threadIdx.x;
    int wv = tid >> 6, lane = tid & 63;
    int quad = lane >> 4, l16 = lane & 15;

    floatx4 acc[2][4];
#pragma unroll
    for (int i = 0; i < 2; i++)
#pragma unroll
        for (int j = 0; j < 4; j++) acc[i][j] = (floatx4){0.f, 0.f, 0.f, 0.f};

    for (int kk = 0; kk < 512; kk += 32) {
        {
            unsigned int* dst = (unsigned int*)sA;
            for (int j = 0; j < 2; j++) {
                int idx = tid + j * 256;
                int m = idx >> 4, kp = idx & 15;
                dst[m * 20 + kp] = ((const unsigned int*)(hB + ((size_t)(t * 32 + m)) * 512 + kk))[kp];
            }
        }
        {
            unsigned int* dst = (unsigned int*)sB;
#pragma unroll
            for (int j = 0; j < 16; j++) {
                int idx = tid + j * 256;
                int n = idx >> 4, kp = idx & 15;
                int gn = n0 + n;
                unsigned int v = 0u;
                if (gn < VV) v = ((const unsigned int*)(WfcB + (size_t)gn * 512 + kk))[kp];
                dst[n * 20 + kp] = v;
            }
        }
        __syncthreads();
        short8 af[2], bf[4];
#pragma unroll
        for (int mt = 0; mt < 2; mt++)
            af[mt] = *(const short8*)(sA + (mt * 16 + l16) * 40 + quad * 8);
#pragma unroll
        for (int nt = 0; nt < 4; nt++) {
            int nl = wv * 64 + nt * 16 + l16;
            bf[nt] = *(const short8*)(sB + nl * 40 + quad * 8);
        }
#pragma unroll
        for (int mt = 0; mt < 2; mt++)
#pragma unroll
            for (int nt = 0; nt < 4; nt++)
                acc[mt][nt] = __builtin_amdgcn_mfma_f32_16x16x32_bf16(af[mt], bf[nt], acc[mt][nt], 0, 0, 0);
        __syncthreads();
    }
#pragma unroll
    for (int mt = 0; mt < 2; mt++) {
#pragma unroll
        for (int r = 0; r < 4; r++) {
            int m = mt * 16 + quad * 4 + r;
            bool active = t < dlen[m];
            float* orow = out + OFF_PRED + ((size_t)m * TT + t) * VV;
#pragma unroll
            for (int nt = 0; nt < 4; nt++) {
                int n = n0 + wv * 64 + nt * 16 + l16;
                if (n < VV) orow[n] = active ? (acc[mt][nt][r] + bfc[n]) : 0.f;
            }
        }
    }
}

// ---------------------------------------------------------------- launch
extern "C" void kernel_launch(void* const* d_in, const int* in_sizes, int n_in,
                              void* d_out, int out_size, void* d_ws, size_t ws_size,
                              hipStream_t stream) {
    const float* img   = (const float*)d_in[0];
    const int*   toks  = (const int*)d_in[1];
    const int*   lens  = (const int*)d_in[2];
    const float* Wenc  = (const float*)d_in[3];
    const float* benc  = (const float*)d_in[4];
    const float* Wdec  = (const float*)d_in[5];
    const float* bdec  = (const float*)d_in[6];
    const float* wfull = (const float*)d_in[7];
    // d_in[8] = b_full (scalar 0; softmax-invariant)
    const float* emb   = (const float*)d_in[9];
    const float* Wih   = (const float*)d_in[10];
    const float* bih   = (const float*)d_in[11];
    const float* Whh   = (const float*)d_in[12];
    const float* bhh   = (const float*)d_in[13];
    const float* Wh0   = (const float*)d_in[14];
    const float* bh0   = (const float*)d_in[15];
    const float* Wc0   = (const float*)d_in[16];
    const float* bc0   = (const float*)d_in[17];
    const float* Wbeta = (const float*)d_in[18];
    const float* bbeta = (const float*)d_in[19];
    const float* Wfc   = (const float*)d_in[20];
    const float* bfc   = (const float*)d_in[21];
    float* out = (float*)d_out;

    // workspace layout
    char* ws = (char*)d_ws;
    int* sidx = (int*)ws;                  ws += 256;
    int* dlen = (int*)ws;                  ws += 256;
    float* c         = (float*)ws;         ws += (size_t)BB * DECD * 4;          // 64 KB
    float* xT        = (float*)ws;         ws += (size_t)2560 * BB * 4;          // 320 KB  [k][b]; tail = hT
    float* hp        = (float*)ws;         ws += (size_t)2560 * BB * 4;          // 320 KB  h-proj (dec|beta)
    float* gpartA    = (float*)ws;         ws += (size_t)2048 * BB * 4;          // 256 KB  h-part of gates
    float* score_raw = (float*)ws;         ws += (size_t)BB * 200 * 4;           // 25.6 KB
    unsigned short* hB = (unsigned short*)ws; ws += (size_t)TT * BB * DECD * 2;  // 1.7 MB
    unsigned int* WfcB = (unsigned int*)ws; ws += (size_t)VV * 512 * 2;          // 10.2 MB
    float* enc_att   = (float*)ws;         ws += (size_t)BB * PP * ATTD * 4;     // 12.8 MB
    float* gbase     = (float*)ws;         ws += (size_t)TT * BB * 2048 * 4;     // 13.4 MB

    k_sort<<<1, 64, 0, stream>>>(toks, lens, sidx, dlen, out);
    k_init<<<32, 256, 0, stream>>>(img, sidx, Wh0, bh0, Wc0, bc0, xT, c);
    k_cvtfc<<<2500, 256, 0, stream>>>(Wfc, WfcB);
    k_enc<<<dim3(98, 2), 256, 0, stream>>>(img, sidx, Wenc, benc, enc_att);
    k_gemb<<<dim3(51, 32), 256, 0, stream>>>(emb, toks, sidx, Wih, bih, bhh, gbase);

    LoopArgs la;
    la.xT = xT; la.hp = hp; la.gpartA = gpartA; la.sraw = score_raw; la.c = c;
    la.hB = hB; la.enc_att = enc_att; la.img = img; la.sidx = sidx; la.dlen = dlen;
    la.gbase = gbase; la.Wdec = Wdec; la.Wbeta = Wbeta; la.Whh = Whh; la.Wih = Wih;
    la.bdec = bdec; la.wfull = wfull; la.bbeta = bbeta; la.out_alpha = out + OFF_ALPHA;
    void* kargs[] = { (void*)&la };
    hipLaunchCooperativeKernel((void*)k_loop, dim3(288), dim3(256), kargs, 0, stream);

    k_pred<<<dim3(TT, 40), 256, 0, stream>>>(hB, (const unsigned short*)WfcB, bfc, dlen, out);
}

// Round 2
// 5332.545 us; speedup vs baseline: 2.1584x; 2.1584x over previous
//
#include <hip/hip_runtime.h>
#include <hip/hip_bf16.h>
#include <cstddef>

#define BB 32
#define PP 196
#define ENCD 2048
#define EMBD 512
#define DECD 512
#define ATTD 512
#define VV 10000
#define LLEN 52
#define TT 51
#define GKC 8    // k-chunks in k_gstep (2560/320)
#define HKC 4    // k-chunks in k_hproj (512/128)

// output offsets (floats)
#define OFF_PRED  0
#define OFF_TOKS  16320000
#define OFF_DLEN  16321664
#define OFF_ALPHA 16321696
#define OFF_SIDX  16641568

typedef __attribute__((ext_vector_type(8))) short short8;
typedef __attribute__((ext_vector_type(4))) float floatx4;

__device__ __forceinline__ float sigmf(float x) { return 1.0f / (1.0f + __expf(-x)); }
__device__ __forceinline__ unsigned short f2bf(float x) {
    __hip_bfloat16 h = __float2bfloat16(x);
    return *(unsigned short*)&h;
}

// ---------------------------------------------------------------- sort
__global__ void k_sort(const int* __restrict__ toks, const int* __restrict__ lens,
                       int* __restrict__ sidx, int* __restrict__ dlen, float* __restrict__ out) {
    __shared__ int s_idx[BB];
    if (threadIdx.x == 0) {
        int idx[BB], ln[BB];
        for (int i = 0; i < BB; i++) { idx[i] = i; ln[i] = lens[i]; }
        for (int i = 1; i < BB; i++) {           // stable insertion sort, descending
            int ci = idx[i], cl = ln[i]; int j = i - 1;
            while (j >= 0 && ln[j] < cl) { ln[j + 1] = ln[j]; idx[j + 1] = idx[j]; j--; }
            ln[j + 1] = cl; idx[j + 1] = ci;
        }
        for (int i = 0; i < BB; i++) {
            s_idx[i] = idx[i];
            sidx[i] = idx[i];
            int d = ln[i] - 1;
            dlen[i] = d;
            out[OFF_DLEN + i] = (float)d;
            out[OFF_SIDX + i] = (float)idx[i];
        }
    }
    __syncthreads();
    for (int i = threadIdx.x; i < BB * LLEN; i += blockDim.x) {
        int b = i / LLEN, l = i % LLEN;
        out[OFF_TOKS + i] = (float)toks[s_idx[b] * LLEN + l];
    }
}

// ---------------------------------------------------------------- mean + h0/c0 (h -> xT tail, transposed)
__global__ void k_init(const float* __restrict__ img, const int* __restrict__ sidx,
                       const float* __restrict__ Wh0, const float* __restrict__ bh0,
                       const float* __restrict__ Wc0, const float* __restrict__ bc0,
                       float* __restrict__ xT, float* __restrict__ c) {
    int b = blockIdx.x;
    int sb = sidx[b];
    __shared__ float smean[ENCD];
    const float* ib = img + (size_t)sb * PP * ENCD;
    for (int e = threadIdx.x; e < ENCD; e += 256) {
        float acc = 0.f;
        for (int p = 0; p < PP; p++) acc += ib[(size_t)p * ENCD + e];
        smean[e] = acc * (1.0f / 196.0f);
    }
    __syncthreads();
    for (int d = threadIdx.x; d < DECD; d += 256) {
        const float* wh = Wh0 + (size_t)d * ENCD;
        const float* wc = Wc0 + (size_t)d * ENCD;
        float ah = bh0[d], ac = bc0[d];
        for (int e = 0; e < ENCD; e++) { float m = smean[e]; ah += m * wh[e]; ac += m * wc[e]; }
        xT[(2048 + d) * BB + b] = ah;     // hT
        c[b * DECD + d] = ac;
    }
}

// ---------------------------------------------------------------- transpose loop weights (k-major)
// WgT[k][d] = k<2048 ? Wih[d][512+k] : Whh[d][k-2048];  k<2560, d<2048
__global__ void k_twg(const float* __restrict__ Wih, const float* __restrict__ Whh,
                      float* __restrict__ WgT) {
    __shared__ float sT[32][33];
    int kt = blockIdx.x, dt = blockIdx.y;
    int tx = threadIdx.x & 31, ty = threadIdx.x >> 5;  // ty 0..7
    for (int j = 0; j < 4; j++) {
        int dd = dt * 32 + ty + j * 8;
        int kk = kt * 32 + tx;
        float v = (kk < 2048) ? Wih[(size_t)dd * 2560 + 512 + kk]
                              : Whh[(size_t)dd * 512 + (kk - 2048)];
        sT[ty + j * 8][tx] = v;
    }
    __syncthreads();
    for (int j = 0; j < 4; j++) {
        int kk = kt * 32 + ty + j * 8;
        int dd = dt * 32 + tx;
        WgT[(size_t)kk * 2048 + dd] = sT[tx][ty + j * 8];
    }
}

// WhT[k][col] = col<512 ? Wdec[col][k] : Wbeta[col-512][k];  k<512, col<2560
__global__ void k_twh(const float* __restrict__ Wdec, const float* __restrict__ Wbeta,
                      float* __restrict__ WhT) {
    __shared__ float sT[32][33];
    int kt = blockIdx.x, ct = blockIdx.y;
    int tx = threadIdx.x & 31, ty = threadIdx.x >> 5;
    for (int j = 0; j < 4; j++) {
        int cc = ct * 32 + ty + j * 8;
        int kk = kt * 32 + tx;
        float v = (cc < 512) ? Wdec[(size_t)cc * 512 + kk]
                             : Wbeta[(size_t)(cc - 512) * 512 + kk];
        sT[ty + j * 8][tx] = v;
    }
    __syncthreads();
    for (int j = 0; j < 4; j++) {
        int kk = kt * 32 + ty + j * 8;
        int cc = ct * 32 + tx;
        WhT[(size_t)kk * 2560 + cc] = sT[tx][ty + j * 8];
    }
}

// WfcB: bf16 convert of Wfc [10000][512], layout unchanged
__global__ void k_cvtfc(const float* __restrict__ Wfc, unsigned int* __restrict__ WfcB) {
    int base = (blockIdx.x * 256 + threadIdx.x) * 4;
    for (int j = 0; j < 4; j++) {
        int ui = base + j;                 // 0 .. 2,560,000
        const float* src = Wfc + (size_t)ui * 2;
        unsigned int lo = f2bf(src[0]), hi = f2bf(src[1]);
        WfcB[ui] = lo | (hi << 16);
    }
}

// ---------------------------------------------------------------- enc_att = img @ W_enc^T + b_enc
// M=6272, N=512, K=2048. grid (98, 2), block 256. 8x8 register tile, 64x256 block tile.
__global__ void k_enc(const float* __restrict__ img, const int* __restrict__ sidx,
                      const float* __restrict__ Wenc, const float* __restrict__ benc,
                      float* __restrict__ enc_att) {
    __shared__ float sA[16][68];
    __shared__ float sW[16][260];
    __shared__ size_t sRB[64];
    int mb = blockIdx.x, c0 = blockIdx.y * 256;
    int tid = threadIdx.x;
    int tm = tid >> 5, tn = tid & 31;
    if (tid < 64) {
        int row = mb * 64 + tid;
        int b = row / PP, p = row % PP;
        sRB[tid] = ((size_t)sidx[b] * PP + p) * ENCD;
    }
    __syncthreads();
    float acc[8][8];
#pragma unroll
    for (int i = 0; i < 8; i++)
#pragma unroll
        for (int j = 0; j < 8; j++) acc[i][j] = 0.f;

    for (int kk = 0; kk < ENCD; kk += 16) {
        {
            int m = tid >> 2, kq = tid & 3;
            float4 v = *(const float4*)(img + sRB[m] + kk + kq * 4);
            sA[kq * 4 + 0][m] = v.x; sA[kq * 4 + 1][m] = v.y;
            sA[kq * 4 + 2][m] = v.z; sA[kq * 4 + 3][m] = v.w;
        }
        {
            int col = c0 + tid;
            const float* wr = Wenc + (size_t)col * ENCD + kk;
#pragma unroll
            for (int j = 0; j < 4; j++) {
                float4 v = *(const float4*)(wr + j * 4);
                sW[j * 4 + 0][tid] = v.x; sW[j * 4 + 1][tid] = v.y;
                sW[j * 4 + 2][tid] = v.z; sW[j * 4 + 3][tid] = v.w;
            }
        }
        __syncthreads();
#pragma unroll
        for (int k = 0; k < 16; k++) {
            float4 a0 = *(const float4*)&sA[k][tm * 8];
            float4 a1 = *(const float4*)&sA[k][tm * 8 + 4];
            float4 w0 = *(const float4*)&sW[k][tn * 4];
            float4 w1 = *(const float4*)&sW[k][128 + tn * 4];
            float av[8] = {a0.x, a0.y, a0.z, a0.w, a1.x, a1.y, a1.z, a1.w};
            float wv[8] = {w0.x, w0.y, w0.z, w0.w, w1.x, w1.y, w1.z, w1.w};
#pragma unroll
            for (int i = 0; i < 8; i++)
#pragma unroll
                for (int j = 0; j < 8; j++) acc[i][j] += av[i] * wv[j];
        }
        __syncthreads();
    }
#pragma unroll
    for (int i = 0; i < 8; i++) {
        int row = mb * 64 + tm * 8 + i;
        float* orow = enc_att + (size_t)row * ATTD + c0;
        int ca = tn * 4, cb = 128 + tn * 4;
        float4 oa = {acc[i][0] + benc[c0 + ca + 0], acc[i][1] + benc[c0 + ca + 1],
                     acc[i][2] + benc[c0 + ca + 2], acc[i][3] + benc[c0 + ca + 3]};
        float4 ob = {acc[i][4] + benc[c0 + cb + 0], acc[i][5] + benc[c0 + cb + 1],
                     acc[i][6] + benc[c0 + cb + 2], acc[i][7] + benc[c0 + cb + 3]};
        *(float4*)(orow + ca) = oa;
        *(float4*)(orow + cb) = ob;
    }
}

// ---------------------------------------------------------------- g_base = emb_t @ W_ih[:, :512]^T + b_ih + b_hh
__global__ void k_gemb(const float* __restrict__ emb, const int* __restrict__ toks,
                       const int* __restrict__ sidx, const float* __restrict__ Wih,
                       const float* __restrict__ bih, const float* __restrict__ bhh,
                       float* __restrict__ gbase) {
    __shared__ float As[32][33];
    __shared__ float Ws[32][65];
    __shared__ size_t rb[32];
    int row0 = blockIdx.x * 32, col0 = blockIdx.y * 64;
    int tid = threadIdx.x;
    int tr = tid & 31, tc = tid >> 5;
    if (tid < 32) {
        int t = blockIdx.x, b = tid;
        int tok = toks[sidx[b] * LLEN + t];
        rb[tid] = (size_t)tok * EMBD;
    }
    __syncthreads();
    float acc[8] = {0, 0, 0, 0, 0, 0, 0, 0};
    for (int kk = 0; kk < EMBD; kk += 32) {
        for (int i = tid; i < 1024; i += 256) {
            int r = i >> 5, k = i & 31;
            As[r][k] = emb[rb[r] + kk + k];
        }
        for (int i = tid; i < 2048; i += 256) {
            int cc = i >> 5, k = i & 31;
            Ws[k][cc] = Wih[(size_t)(col0 + cc) * (EMBD + ENCD) + kk + k];
        }
        __syncthreads();
        for (int k = 0; k < 32; k++) {
            float a = As[tr][k];
#pragma unroll
            for (int j = 0; j < 8; j++) acc[j] += a * Ws[k][tc * 8 + j];
        }
        __syncthreads();
    }
    int row = row0 + tr;
    float* crow = gbase + (size_t)row * 2048 + col0 + tc * 8;
#pragma unroll
    for (int j = 0; j < 8; j++) {
        int col = col0 + tc * 8 + j;
        crow[j] = acc[j] + bih[col] + bhh[col];
    }
}

// ---------------------------------------------------------------- per-step: h projection (dec_att + beta gate, partials)
// hp[kc][2560][32]; grid (20 colchunk of 128, 2 bgrp of 16, HKC kc of 128), block 256.
// Weight tile read by only 2 b-groups (vs 4 before): WhT traffic 10.4 MB/step.
__global__ void k_hproj(const float* __restrict__ xT, const float* __restrict__ WhT,
                        float* __restrict__ hp) {
    int cl = threadIdx.x & 127, bh = threadIdx.x >> 7;
    int col = blockIdx.x * 128 + cl;
    int b0 = blockIdx.y * 16 + bh * 8;
    int k0 = blockIdx.z * 128;
    const float* Wp = WhT + (size_t)k0 * 2560 + col;
    const float* Xp = xT + (size_t)(2048 + k0) * BB + b0;
    float a0=0.f,a1=0.f,a2=0.f,a3=0.f,a4=0.f,a5=0.f,a6=0.f,a7=0.f;
#pragma unroll 4
    for (int k = 0; k < 128; k++) {
        float w = Wp[(size_t)k * 2560];
        const float* x = Xp + k * BB;
        float4 xa = *(const float4*)x;
        float4 xb = *(const float4*)(x + 4);
        a0 += w * xa.x; a1 += w * xa.y; a2 += w * xa.z; a3 += w * xa.w;
        a4 += w * xb.x; a5 += w * xb.y; a6 += w * xb.z; a7 += w * xb.w;
    }
    float* gp = hp + ((size_t)(blockIdx.z * 2560 + col)) * BB + b0;
    *(float4*)gp = make_float4(a0, a1, a2, a3);
    *(float4*)(gp + 4) = make_float4(a4, a5, a6, a7);
}

// ---------------------------------------------------------------- per-step: raw attention scores
// grid (32 b, 4 p-quarter), block 256. Writes sraw[b*200+p].
__global__ void k_score(const float* __restrict__ hp, const float* __restrict__ bdec,
                        const float* __restrict__ wfull, const float* __restrict__ enc_att,
                        float* __restrict__ sraw) {
    int b = blockIdx.x, pq = blockIdx.y, tid = threadIdx.x;
    __shared__ float sdec[512], swf[512];
    for (int a = tid; a < 512; a += 256) {
        float v = bdec[a];
#pragma unroll
        for (int kc = 0; kc < HKC; kc++) v += hp[(size_t)(kc * 2560 + a) * BB + b];
        sdec[a] = v;
        swf[a] = wfull[a];
    }
    __syncthreads();
    int wv = tid >> 6, ln = tid & 63;
    const float* eb = enc_att + (size_t)b * PP * ATTD;
    const int p1 = pq * 49 + 49;
    for (int p = pq * 49 + wv; p < p1; p += 4) {
        const float* er = eb + (size_t)p * ATTD;
        float acc = 0.f;
#pragma unroll
        for (int i = 0; i < 8; i++) {
            int a = ln + i * 64;
            acc += fmaxf(er[a] + sdec[a], 0.f) * swf[a];
        }
#pragma unroll
        for (int off = 32; off; off >>= 1) acc += __shfl_down(acc, off);
        if (ln == 0) sraw[b * 200 + p] = acc;
    }
}

// ---------------------------------------------------------------- per-step: softmax (redundant) + awe + beta gate -> xT
// grid (32 b, 16 ec of 128 e), block 256 = 2 p-groups x 128 e. Also writes alpha output (ec==0).
__global__ void k_awe(int t, const float* __restrict__ img, const int* __restrict__ sidx,
                      const float* __restrict__ sraw, const float* __restrict__ hp,
                      const float* __restrict__ bbeta, const int* __restrict__ dlen,
                      float* __restrict__ xT, float* __restrict__ out_alpha) {
    int b = blockIdx.x, ec = blockIdx.y, tid = threadIdx.x;
    __shared__ float sal[200];
    __shared__ float sred[256];
    __shared__ float spart[256];
    __shared__ int ssb;
    if (tid == 0) ssb = sidx[b];
    float v = (tid < PP) ? sraw[b * 200 + tid] : -1e30f;
    sred[tid] = v;
    __syncthreads();
    for (int s = 128; s; s >>= 1) { if (tid < s) sred[tid] = fmaxf(sred[tid], sred[tid + s]); __syncthreads(); }
    float mx = sred[0];
    __syncthreads();
    float e = (tid < PP) ? __expf(v - mx) : 0.f;
    sred[tid] = e;
    __syncthreads();
    for (int s = 128; s; s >>= 1) { if (tid < s) sred[tid] += sred[tid + s]; __syncthreads(); }
    float inv = 1.f / sred[0];
    if (tid < PP) sal[tid] = e * inv;
    __syncthreads();
    int pg = tid >> 7, el = tid & 127;
    int eo = ec * 128 + el;
    const float* ib = img + (size_t)ssb * PP * ENCD + eo;
    float acc = 0.f;
    const int p0 = pg * 98;
#pragma unroll 7
    for (int p = 0; p < 98; p++) acc += sal[p0 + p] * ib[(size_t)(p0 + p) * ENCD];
    spart[tid] = acc;
    __syncthreads();
    if (tid < 128) {
        float awe = spart[tid] + spart[128 + tid];
        int e2 = ec * 128 + tid;
        float graw = bbeta[e2];
#pragma unroll
        for (int kc = 0; kc < HKC; kc++) graw += hp[(size_t)(kc * 2560 + 512 + e2) * BB + b];
        xT[(size_t)e2 * BB + b] = awe * sigmf(graw);
    }
    if (ec == 0 && tid < PP) {
        bool act = t < dlen[b];
        out_alpha[((size_t)b * TT + t) * PP + tid] = act ? sal[tid] : 0.f;
    }
}

// ---------------------------------------------------------------- per-step: gate-GEMM partials
// C[d=2048][b=32] = sum_k WgT[k][d]*xT[k][b]; grid (16 dchunk of 128, 2 bgrp of 16, GKC kc), block 256.
// Weight tile read by only 2 b-groups (vs 4 before): WgT traffic 42 MB/step.
__global__ void k_gstep(const float* __restrict__ xT, const float* __restrict__ WgT,
                        float* __restrict__ gpart) {
    int cl = threadIdx.x & 127, bh = threadIdx.x >> 7;
    int d = blockIdx.x * 128 + cl;
    int b0 = blockIdx.y * 16 + bh * 8;
    int k0 = blockIdx.z * 320;
    const float* Wp = WgT + (size_t)k0 * 2048 + d;
    const float* Xp = xT + k0 * BB + b0;
    float a0=0.f,a1=0.f,a2=0.f,a3=0.f,a4=0.f,a5=0.f,a6=0.f,a7=0.f;
#pragma unroll 4
    for (int k = 0; k < 320; k++) {
        float w = Wp[(size_t)k * 2048];
        const float* x = Xp + k * BB;
        float4 xa = *(const float4*)x;
        float4 xb = *(const float4*)(x + 4);
        a0 += w * xa.x; a1 += w * xa.y; a2 += w * xa.z; a3 += w * xa.w;
        a4 += w * xb.x; a5 += w * xb.y; a6 += w * xb.z; a7 += w * xb.w;
    }
    float* gp = gpart + ((size_t)(blockIdx.z * 2048 + d)) * BB + b0;
    *(float4*)gp = make_float4(a0, a1, a2, a3);
    *(float4*)(gp + 4) = make_float4(a4, a5, a6, a7);
}

// ---------------------------------------------------------------- per-step: LSTM cell update
__global__ void k_update(int t, const float* __restrict__ gbase, const float* __restrict__ gpart,
                         const int* __restrict__ dlen, float* __restrict__ xT,
                         float* __restrict__ c, unsigned short* __restrict__ hB) {
    int b = blockIdx.x >> 1;
    int d = (blockIdx.x & 1) * 256 + threadIdx.x;
    bool active = t < dlen[b];
    const float* gb = gbase + ((size_t)t * BB + b) * 2048;
    float gi = gb[d], gf = gb[d + 512], gg = gb[d + 1024], go = gb[d + 1536];
#pragma unroll
    for (int kc = 0; kc < GKC; kc++) {
        const float* gp = gpart + ((size_t)kc * 2048) * BB + b;
        gi += gp[(size_t)d * BB];
        gf += gp[(size_t)(512 + d) * BB];
        gg += gp[(size_t)(1024 + d) * BB];
        go += gp[(size_t)(1536 + d) * BB];
    }
    float i_ = sigmf(gi), f_ = sigmf(gf), g_ = tanhf(gg), o_ = sigmf(go);
    float cv = c[b * DECD + d];
    float cn = f_ * cv + i_ * g_;
    float hn = o_ * tanhf(cn);
    float hv;
    if (active) { c[b * DECD + d] = cn; xT[(2048 + d) * BB + b] = hn; hv = hn; }
    else hv = xT[(2048 + d) * BB + b];
    hB[((size_t)t * BB + b) * DECD + d] = f2bf(hv);
}

// ---------------------------------------------------------------- predictions via bf16 MFMA
__global__ void k_pred(const unsigned short* __restrict__ hB, const unsigned short* __restrict__ WfcB,
                       const float* __restrict__ bfc, const int* __restrict__ dlen,
                       float* __restrict__ out) {
    __shared__ unsigned short sA[32 * 40];
    __shared__ unsigned short sB[256 * 40];
    int t = blockIdx.x, n0 = blockIdx.y * 256;
    int tid = threadIdx.x;
    int wv = tid >> 6, lane = tid & 63;
    int quad = lane >> 4, l16 = lane & 15;

    floatx4 acc[2][4];
#pragma unroll
    for (int i = 0; i < 2; i++)
#pragma unroll
        for (int j = 0; j < 4; j++) acc[i][j] = (floatx4){0.f, 0.f, 0.f, 0.f};

    for (int kk = 0; kk < 512; kk += 32) {
        {
            unsigned int* dst = (unsigned int*)sA;
            for (int j = 0; j < 2; j++) {
                int idx = tid + j * 256;
                int m = idx >> 4, kp = idx & 15;
                dst[m * 20 + kp] = ((const unsigned int*)(hB + ((size_t)(t * 32 + m)) * 512 + kk))[kp];
            }
        }
        {
            unsigned int* dst = (unsigned int*)sB;
#pragma unroll
            for (int j = 0; j < 16; j++) {
                int idx = tid + j * 256;
                int n = idx >> 4, kp = idx & 15;
                int gn = n0 + n;
                unsigned int v = 0u;
                if (gn < VV) v = ((const unsigned int*)(WfcB + (size_t)gn * 512 + kk))[kp];
                dst[n * 20 + kp] = v;
            }
        }
        __syncthreads();
        short8 af[2], bf[4];
#pragma unroll
        for (int mt = 0; mt < 2; mt++)
            af[mt] = *(const short8*)(sA + (mt * 16 + l16) * 40 + quad * 8);
#pragma unroll
        for (int nt = 0; nt < 4; nt++) {
            int nl = wv * 64 + nt * 16 + l16;
            bf[nt] = *(const short8*)(sB + nl * 40 + quad * 8);
        }
#pragma unroll
        for (int mt = 0; mt < 2; mt++)
#pragma unroll
            for (int nt = 0; nt < 4; nt++)
                acc[mt][nt] = __builtin_amdgcn_mfma_f32_16x16x32_bf16(af[mt], bf[nt], acc[mt][nt], 0, 0, 0);
        __syncthreads();
    }
#pragma unroll
    for (int mt = 0; mt < 2; mt++) {
#pragma unroll
        for (int r = 0; r < 4; r++) {
            int m = mt * 16 + quad * 4 + r;
            bool active = t < dlen[m];
            float* orow = out + OFF_PRED + ((size_t)m * TT + t) * VV;
#pragma unroll
            for (int nt = 0; nt < 4; nt++) {
                int n = n0 + wv * 64 + nt * 16 + l16;
                if (n < VV) orow[n] = active ? (acc[mt][nt][r] + bfc[n]) : 0.f;
            }
        }
    }
}

// ---------------------------------------------------------------- launch
extern "C" void kernel_launch(void* const* d_in, const int* in_sizes, int n_in,
                              void* d_out, int out_size, void* d_ws, size_t ws_size,
                              hipStream_t stream) {
    const float* img   = (const float*)d_in[0];
    const int*   toks  = (const int*)d_in[1];
    const int*   lens  = (const int*)d_in[2];
    const float* Wenc  = (const float*)d_in[3];
    const float* benc  = (const float*)d_in[4];
    const float* Wdec  = (const float*)d_in[5];
    const float* bdec  = (const float*)d_in[6];
    const float* wfull = (const float*)d_in[7];
    // d_in[8] = b_full (scalar 0; softmax-invariant)
    const float* emb   = (const float*)d_in[9];
    const float* Wih   = (const float*)d_in[10];
    const float* bih   = (const float*)d_in[11];
    const float* Whh   = (const float*)d_in[12];
    const float* bhh   = (const float*)d_in[13];
    const float* Wh0   = (const float*)d_in[14];
    const float* bh0   = (const float*)d_in[15];
    const float* Wc0   = (const float*)d_in[16];
    const float* bc0   = (const float*)d_in[17];
    const float* Wbeta = (const float*)d_in[18];
    const float* bbeta = (const float*)d_in[19];
    const float* Wfc   = (const float*)d_in[20];
    const float* bfc   = (const float*)d_in[21];
    float* out = (float*)d_out;

    // workspace layout
    char* ws = (char*)d_ws;
    int* sidx = (int*)ws;                  ws += 256;
    int* dlen = (int*)ws;                  ws += 256;
    float* c        = (float*)ws;          ws += (size_t)BB * DECD * 4;          // 64 KB
    float* xT       = (float*)ws;          ws += (size_t)2560 * BB * 4;          // 320 KB  [k][b]; tail = hT
    float* hp       = (float*)ws;          ws += (size_t)HKC * 2560 * BB * 4;    // 1.3 MB  hproj partials
    float* sraw     = (float*)ws;          ws += (size_t)BB * 200 * 4;           // 25 KB
    float* gpart    = (float*)ws;          ws += (size_t)GKC * 2048 * BB * 4;    // 2 MB
    unsigned short* hB = (unsigned short*)ws; ws += (size_t)TT * BB * DECD * 2;  // 1.7 MB
    float* WgT      = (float*)ws;          ws += (size_t)2560 * 2048 * 4;        // 21 MB
    float* WhT      = (float*)ws;          ws += (size_t)512 * 2560 * 4;         // 5.2 MB
    unsigned int* WfcB = (unsigned int*)ws; ws += (size_t)VV * 512 * 2;          // 10.2 MB
    float* enc_att  = (float*)ws;          ws += (size_t)BB * PP * ATTD * 4;     // 12.8 MB
    float* gbase    = (float*)ws;          ws += (size_t)TT * BB * 2048 * 4;     // 13.4 MB

    k_sort<<<1, 64, 0, stream>>>(toks, lens, sidx, dlen, out);
    k_init<<<32, 256, 0, stream>>>(img, sidx, Wh0, bh0, Wc0, bc0, xT, c);
    k_twg<<<dim3(80, 64), 256, 0, stream>>>(Wih, Whh, WgT);
    k_twh<<<dim3(16, 80), 256, 0, stream>>>(Wdec, Wbeta, WhT);
    k_cvtfc<<<2500, 256, 0, stream>>>(Wfc, WfcB);
    k_enc<<<dim3(98, 2), 256, 0, stream>>>(img, sidx, Wenc, benc, enc_att);
    k_gemb<<<dim3(51, 32), 256, 0, stream>>>(emb, toks, sidx, Wih, bih, bhh, gbase);

    for (int t = 0; t < TT; t++) {
        k_hproj<<<dim3(20, 2, HKC), 256, 0, stream>>>(xT, WhT, hp);
        k_score<<<dim3(32, 4), 256, 0, stream>>>(hp, bdec, wfull, enc_att, sraw);
        k_awe<<<dim3(32, 16), 256, 0, stream>>>(t, img, sidx, sraw, hp, bbeta, dlen,
                                                xT, out + OFF_ALPHA);
        k_gstep<<<dim3(16, 2, GKC), 256, 0, stream>>>(xT, WgT, gpart);
        k_update<<<64, 256, 0, stream>>>(t, gbase, gpart, dlen, xT, c, hB);
    }

    k_pred<<<dim3(TT, 40), 256, 0, stream>>>(hB, (const unsigned short*)WfcB, bfc, dlen, out);
}